// Round 3
// baseline (585.640 us; speedup 1.0000x reference)
//
#include <hip/hip_runtime.h>

// PulseFloatingPointEncoder: per element emit 8 fp32 flags
// [sign, e3, e2, e1, e0, m2, m1, m0] of a truncated e4m3-style encoding.
// E_BITS=4, M_BITS=3, N_INT=10, N_DEC=10, BIAS=7, START_EXP=17, SUB_START=16.
//
// V4: structure ablation — no LDS, no barriers, no loop. Adjacent lane pairs
// redundantly encode the same input element (compute is ~25 VALU ops; doubling
// it costs ~10 us chip-wide) so that every lane stores exactly one contiguous
// 16-B float4: thread t writes out4[t] = (t&1) ? hi(e) : lo(e), e = t>>1.
// This makes the store stream identical in shape to the 6.2 TB/s fill kernel.
// Loads are 2-lane-broadcast, 128 B contiguous per wave instruction.

typedef float f32x4 __attribute__((ext_vector_type(4)));

__device__ __forceinline__ void encode_one(float x, f32x4& lo, f32x4& hi) {
    float sign = (x < 0.0f) ? 1.0f : 0.0f;   // note: -0.0f -> 0 (matches ref x<0)
    unsigned ub = __float_as_uint(x) & 0x7fffffffu;
    float a = __uint_as_float(ub);
    int e_lead = (int)(ub >> 23) - 127;      // floor(log2 a) for normals; <=-127 for subnorm/zero

    int ec, mant;
    if (__builtin_expect(e_lead >= 10, 0)) {
        // a >= 1024 (or inf/nan): faithful emulation of the reference greedy scan.
        float V = a;
        int has_fired = 0, d0 = 0, d1 = 0, d2 = 0;
        int e_reg = 0, m0 = 0, m1 = 0, m2 = 0;
        for (int t = 0; t < 20; ++t) {
            float thr = __builtin_exp2f((float)(9 - t));   // exact powers of two
            int s = (V >= thr) ? 1 : 0;
            if (s) V -= thr;                                // exact: V - s*thr
            int fs = s & (has_fired ^ 1);
            int active = (t < 16) ? 1 : 0;
            int counter = (16 - t) > 0 ? (16 - t) : 0;
            if (fs & active) e_reg |= (counter & 15);
            if (s) { m0 |= d0; m1 |= d1; m2 |= d2; }
            int vfs = fs & active;
            d2 = d1; d1 = d0; d0 = vfs;
            has_fired |= vfs;
            if (t >= 16 && t <= 18) {
                int bit = s & (has_fired ^ 1);
                if (t == 16) m0 |= bit; else if (t == 17) m1 |= bit; else m2 |= bit;
            }
        }
        ec = e_reg;
        mant = (m0 << 2) | (m1 << 1) | m2;
    } else {
        bool norm = (e_lead >= -6);
        bool sub  = (e_lead >= -10) & !norm;
        // normal: exponent code (7+e_lead)&15, mantissa = top 3 fraction bits (truncate)
        int ec_n   = (7 + e_lead) & 15;
        int mant_n = (int)(ub >> 20) & 7;
        // subnormal range [2^-10, 2^-6): bits at weights 2^-7..2^-9
        int mant_s = ((int)(a * 512.0f)) & 7;   // a*512 in [0.5, 8), exact scaling, trunc
        ec   = norm ? ec_n : 0;
        mant = norm ? mant_n : (sub ? mant_s : 0);
    }

    lo.x = sign;
    lo.y = (float)((ec >> 3) & 1);   // e_out is e_reg reversed => MSB first
    lo.z = (float)((ec >> 2) & 1);
    lo.w = (float)((ec >> 1) & 1);
    hi.x = (float)(ec & 1);
    hi.y = (float)((mant >> 2) & 1); // m_reg[0] = most significant mantissa bit
    hi.z = (float)((mant >> 1) & 1);
    hi.w = (float)(mant & 1);
}

// One thread per OUTPUT float4 slot. nslots = 2*n. Even lane of each pair
// emits lo, odd lane emits hi, of the shared element e = t>>1.
__global__ __launch_bounds__(256) void pulse_encode_kernel(
        const float* __restrict__ in, f32x4* __restrict__ out4, int nslots) {
    int t = blockIdx.x * 256 + threadIdx.x;
    if (t >= nslots) return;
    float x = in[t >> 1];
    f32x4 lo, hi;
    encode_one(x, lo, hi);
    f32x4 val = (t & 1) ? hi : lo;
    __builtin_nontemporal_store(val, &out4[t]);
}

extern "C" void kernel_launch(void* const* d_in, const int* in_sizes, int n_in,
                              void* d_out, int out_size, void* d_ws, size_t ws_size,
                              hipStream_t stream) {
    const float* x = (const float*)d_in[0];
    f32x4* out = (f32x4*)d_out;
    int n = in_sizes[0];                  // 8*2048*1024 = 16,777,216
    int nslots = 2 * n;                   // one float4 per thread
    int blocks = (nslots + 255) / 256;
    pulse_encode_kernel<<<blocks, 256, 0, stream>>>(x, out, nslots);
}

// Round 4
// 561.304 us; speedup vs baseline: 1.0434x; 1.0434x over previous
//
#include <hip/hip_runtime.h>

// PulseFloatingPointEncoder: per element emit 8 fp32 flags
// [sign, e3, e2, e1, e0, m2, m1, m0] of a truncated e4m3-style encoding.
// E_BITS=4, M_BITS=3, N_INT=10, N_DEC=10, BIAS=7, START_EXP=17, SUB_START=16.
//
// V5: V2's memory shape at MAX OCCUPANCY. 2 elems/thread (float2 load,
// 8 B/lane coalesced), 16 KiB LDS/block (vs V2's 32 KiB) and
// __launch_bounds__(256, 8) forcing VGPR<=64 -> 8 blocks/CU = 32 waves/CU
// (V2 was LDS-capped at 20). Same verified XOR-swizzled LDS staging so
// global stores are contiguous 1 KiB/wave-instruction; nt hints kept (V2
// config). Theory: write throughput is outstanding-store (occupancy) bound.

typedef float  f32x4 __attribute__((ext_vector_type(4)));
typedef float  f32x2 __attribute__((ext_vector_type(2)));

__device__ __forceinline__ void encode_one(float x, f32x4& lo, f32x4& hi) {
    float sign = (x < 0.0f) ? 1.0f : 0.0f;   // note: -0.0f -> 0 (matches ref x<0)
    unsigned ub = __float_as_uint(x) & 0x7fffffffu;
    float a = __uint_as_float(ub);
    int e_lead = (int)(ub >> 23) - 127;      // floor(log2 a) for normals; <=-127 for subnorm/zero

    int ec, mant;
    if (__builtin_expect(e_lead >= 10, 0)) {
        // a >= 1024 (or inf/nan): faithful emulation of the reference greedy scan.
        float V = a;
        int has_fired = 0, d0 = 0, d1 = 0, d2 = 0;
        int e_reg = 0, m0 = 0, m1 = 0, m2 = 0;
        for (int t = 0; t < 20; ++t) {
            float thr = __builtin_exp2f((float)(9 - t));   // exact powers of two
            int s = (V >= thr) ? 1 : 0;
            if (s) V -= thr;                                // exact: V - s*thr
            int fs = s & (has_fired ^ 1);
            int active = (t < 16) ? 1 : 0;
            int counter = (16 - t) > 0 ? (16 - t) : 0;
            if (fs & active) e_reg |= (counter & 15);
            if (s) { m0 |= d0; m1 |= d1; m2 |= d2; }
            int vfs = fs & active;
            d2 = d1; d1 = d0; d0 = vfs;
            has_fired |= vfs;
            if (t >= 16 && t <= 18) {
                int bit = s & (has_fired ^ 1);
                if (t == 16) m0 |= bit; else if (t == 17) m1 |= bit; else m2 |= bit;
            }
        }
        ec = e_reg;
        mant = (m0 << 2) | (m1 << 1) | m2;
    } else {
        bool norm = (e_lead >= -6);
        bool sub  = (e_lead >= -10) & !norm;
        // normal: exponent code (7+e_lead)&15, mantissa = top 3 fraction bits (truncate)
        int ec_n   = (7 + e_lead) & 15;
        int mant_n = (int)(ub >> 20) & 7;
        // subnormal range [2^-10, 2^-6): bits at weights 2^-7..2^-9
        int mant_s = ((int)(a * 512.0f)) & 7;   // a*512 in [0.5, 8), exact scaling, trunc
        ec   = norm ? ec_n : 0;
        mant = norm ? mant_n : (sub ? mant_s : 0);
    }

    lo.x = sign;
    lo.y = (float)((ec >> 3) & 1);   // e_out is e_reg reversed => MSB first
    lo.z = (float)((ec >> 2) & 1);
    lo.w = (float)((ec >> 1) & 1);
    hi.x = (float)(ec & 1);
    hi.y = (float)((mant >> 2) & 1); // m_reg[0] = most significant mantissa bit
    hi.z = (float)((mant >> 1) & 1);
    hi.w = (float)(mant & 1);
}

// 256 threads/block, tile = 512 elements (2/thread from one 8-B load).
// Output per tile: 1024 f32x4 slots (16 KiB LDS).
//
// LDS swizzle: slot s stored at s ^ ((s>>3)&7).
// Writer (thread t, slots 4t..4t+3): per ds_write_b128 instruction (fixed j),
// s%8 in {j, j^4} and key (s>>3)&7 cycles over 0..7 every 2 lanes ->
// (s%8)^key uniform over all 8 4-bank groups (8 lanes each) = balanced.
// Reader (slot t+256k): s%8 = t%8, key = (t>>3)&7; over 64 lanes the pair
// covers all 64 combos -> uniform 8/group = balanced.
__global__ __launch_bounds__(256, 8) void pulse_encode_kernel(
        const f32x2* __restrict__ in2, f32x4* __restrict__ out4) {
    __shared__ f32x4 lds[1024];
    const int t = threadIdx.x;
    const int tile = blockIdx.x;

    f32x2 v = __builtin_nontemporal_load(&in2[tile * 256 + t]);

    // Encode + stage one element at a time to keep register footprint small.
    {
        f32x4 lo, hi;
        encode_one(v.x, lo, hi);
        int s0 = 4 * t;
        lds[s0 ^ ((s0 >> 3) & 7)] = lo;
        int s1 = 4 * t + 1;
        lds[s1 ^ ((s1 >> 3) & 7)] = hi;
    }
    {
        f32x4 lo, hi;
        encode_one(v.y, lo, hi);
        int s2 = 4 * t + 2;
        lds[s2 ^ ((s2 >> 3) & 7)] = lo;
        int s3 = 4 * t + 3;
        lds[s3 ^ ((s3 >> 3) & 7)] = hi;
    }

    __syncthreads();

    const int obase = tile * 1024;
#pragma unroll
    for (int k = 0; k < 4; ++k) {
        int s = t + 256 * k;
        f32x4 val = lds[s ^ ((s >> 3) & 7)];
        __builtin_nontemporal_store(val, &out4[obase + s]);
    }
}

// Tail kernel (n not a multiple of 512): scalar path.
__global__ __launch_bounds__(256) void pulse_encode_tail(
        const float* __restrict__ in, f32x4* __restrict__ out, int n) {
    int i = blockIdx.x * 256 + threadIdx.x;
    if (i >= n) return;
    f32x4 lo, hi;
    encode_one(in[i], lo, hi);
    out[2 * i]     = lo;
    out[2 * i + 1] = hi;
}

extern "C" void kernel_launch(void* const* d_in, const int* in_sizes, int n_in,
                              void* d_out, int out_size, void* d_ws, size_t ws_size,
                              hipStream_t stream) {
    const float* x = (const float*)d_in[0];
    f32x4* out = (f32x4*)d_out;
    int n = in_sizes[0];                  // 8*2048*1024 = 16,777,216
    int ntiles = n / 512;                 // full 512-element tiles
    if (ntiles > 0) {
        pulse_encode_kernel<<<ntiles, 256, 0, stream>>>(
            (const f32x2*)x, out);
    }
    int done = ntiles * 512;
    int rem = n - done;
    if (rem > 0) {
        int tb = (rem + 255) / 256;
        pulse_encode_tail<<<tb, 256, 0, stream>>>(x + done, out + 2 * done, rem);
    }
}

// Round 5
// 551.311 us; speedup vs baseline: 1.0623x; 1.0181x over previous
//
#include <hip/hip_runtime.h>

// PulseFloatingPointEncoder: per element emit 8 fp32 flags
// [sign, e3, e2, e1, e0, m2, m1, m0] of a truncated e4m3-style encoding.
// E_BITS=4, M_BITS=3, N_INT=10, N_DEC=10, BIAS=7, START_EXP=17, SUB_START=16.
//
// V6 == V2 (best measured: 553.5 us). Session ablations (nt policy, load
// latency, store shape, LDS structure, occupancy) were all neutral within
// +-2%; the bench floor is harness poison (~343 us fill + small restores)
// plus ~110-130 us encode vs a 93 us mandatory-traffic roofline. Restoring
// the best-verified configuration:
//  - float4 loads (16 B/lane coalesced)
//  - LDS-staged XOR-swizzled output (bank-conflict-free both phases) so
//    global stores are contiguous 16 B/lane (1 KiB per wave instruction)
//  - nontemporal hints on the streaming load/store
//  - one-shot blocks, 1024 elements/block (32 KiB LDS, 20 waves/CU)

typedef float f32x4 __attribute__((ext_vector_type(4)));

__device__ __forceinline__ void encode_one(float x, f32x4& lo, f32x4& hi) {
    float sign = (x < 0.0f) ? 1.0f : 0.0f;   // note: -0.0f -> 0 (matches ref x<0)
    unsigned ub = __float_as_uint(x) & 0x7fffffffu;
    float a = __uint_as_float(ub);
    int e_lead = (int)(ub >> 23) - 127;      // floor(log2 a) for normals; <=-127 for subnorm/zero

    int ec, mant;
    if (__builtin_expect(e_lead >= 10, 0)) {
        // a >= 1024 (or inf/nan): faithful emulation of the reference greedy scan.
        float V = a;
        int has_fired = 0, d0 = 0, d1 = 0, d2 = 0;
        int e_reg = 0, m0 = 0, m1 = 0, m2 = 0;
        for (int t = 0; t < 20; ++t) {
            float thr = __builtin_exp2f((float)(9 - t));   // exact powers of two
            int s = (V >= thr) ? 1 : 0;
            if (s) V -= thr;                                // exact: V - s*thr
            int fs = s & (has_fired ^ 1);
            int active = (t < 16) ? 1 : 0;
            int counter = (16 - t) > 0 ? (16 - t) : 0;
            if (fs & active) e_reg |= (counter & 15);
            if (s) { m0 |= d0; m1 |= d1; m2 |= d2; }
            int vfs = fs & active;
            d2 = d1; d1 = d0; d0 = vfs;
            has_fired |= vfs;
            if (t >= 16 && t <= 18) {
                int bit = s & (has_fired ^ 1);
                if (t == 16) m0 |= bit; else if (t == 17) m1 |= bit; else m2 |= bit;
            }
        }
        ec = e_reg;
        mant = (m0 << 2) | (m1 << 1) | m2;
    } else {
        bool norm = (e_lead >= -6);
        bool sub  = (e_lead >= -10) & !norm;
        // normal: exponent code (7+e_lead)&15, mantissa = top 3 fraction bits (truncate)
        int ec_n   = (7 + e_lead) & 15;
        int mant_n = (int)(ub >> 20) & 7;
        // subnormal range [2^-10, 2^-6): bits at weights 2^-7..2^-9
        int mant_s = ((int)(a * 512.0f)) & 7;   // a*512 in [0.5, 8), exact scaling, trunc
        ec   = norm ? ec_n : 0;
        mant = norm ? mant_n : (sub ? mant_s : 0);
    }

    lo.x = sign;
    lo.y = (float)((ec >> 3) & 1);   // e_out is e_reg reversed => MSB first
    lo.z = (float)((ec >> 2) & 1);
    lo.w = (float)((ec >> 1) & 1);
    hi.x = (float)(ec & 1);
    hi.y = (float)((mant >> 2) & 1); // m_reg[0] = most significant mantissa bit
    hi.z = (float)((mant >> 1) & 1);
    hi.w = (float)(mant & 1);
}

// Main kernel: 256 threads/block, 4 elements/thread -> 1024 elements/block.
// Output per block: 2048 f32x4 slots (32 KiB), staged in LDS so the global
// stores are lane-contiguous dwordx4 (1 KiB per wave instruction).
//
// LDS swizzle: slot s stored at s ^ ((s>>3)&7). Writer (thread t, slots
// 8t..8t+7): xor key = t&7 -> per ds_write_b128 instruction, lanes spread
// evenly over the 8 4-bank groups (conflict-free). Reader (slot t+256k):
// xor key = (t>>3)&7, same balanced property.
__global__ __launch_bounds__(256) void pulse_encode_kernel(
        const f32x4* __restrict__ in4, f32x4* __restrict__ out4) {
    __shared__ f32x4 lds[2048];
    const int t = threadIdx.x;
    const int blk = blockIdx.x;

    f32x4 v = __builtin_nontemporal_load(&in4[blk * 256 + t]);

    f32x4 lo0, hi0, lo1, hi1, lo2, hi2, lo3, hi3;
    encode_one(v.x, lo0, hi0);
    encode_one(v.y, lo1, hi1);
    encode_one(v.z, lo2, hi2);
    encode_one(v.w, lo3, hi3);

    const int base = t * 8;
    const int sw = t & 7;        // == ((base+j)>>3)&7 for j in [0,8)
    lds[(base + 0) ^ sw] = lo0;
    lds[(base + 1) ^ sw] = hi0;
    lds[(base + 2) ^ sw] = lo1;
    lds[(base + 3) ^ sw] = hi1;
    lds[(base + 4) ^ sw] = lo2;
    lds[(base + 5) ^ sw] = hi2;
    lds[(base + 6) ^ sw] = lo3;
    lds[(base + 7) ^ sw] = hi3;

    __syncthreads();

    const int obase = blk * 2048;
    const int rsw = (t >> 3) & 7;
#pragma unroll
    for (int k = 0; k < 8; ++k) {
        int s = t + 256 * k;
        f32x4 val = lds[s ^ rsw];
        __builtin_nontemporal_store(val, &out4[obase + s]);
    }
}

// Tail kernel (n not a multiple of 1024): scalar path.
__global__ __launch_bounds__(256) void pulse_encode_tail(
        const float* __restrict__ in, f32x4* __restrict__ out, int n) {
    int i = blockIdx.x * 256 + threadIdx.x;
    if (i >= n) return;
    f32x4 lo, hi;
    encode_one(in[i], lo, hi);
    out[2 * i]     = lo;
    out[2 * i + 1] = hi;
}

extern "C" void kernel_launch(void* const* d_in, const int* in_sizes, int n_in,
                              void* d_out, int out_size, void* d_ws, size_t ws_size,
                              hipStream_t stream) {
    const float* x = (const float*)d_in[0];
    f32x4* out = (f32x4*)d_out;
    int n = in_sizes[0];                  // 8*2048*1024 = 16,777,216
    int nblocks = n / 1024;               // full 1024-element blocks
    if (nblocks > 0) {
        pulse_encode_kernel<<<nblocks, 256, 0, stream>>>(
            (const f32x4*)x, out);
    }
    int done = nblocks * 1024;
    int rem = n - done;
    if (rem > 0) {
        int tb = (rem + 255) / 256;
        pulse_encode_tail<<<tb, 256, 0, stream>>>(x + done, out + 2 * done, rem);
    }
}